// Round 1
// baseline (454.721 us; speedup 1.0000x reference)
//
#include <hip/hip_runtime.h>
#include <hip/hip_bf16.h>
#include <cstddef>

#define B_   2
#define S_   2048
#define HID_ 1152
#define NH_  16
#define NKV_ 4
#define HD_  72
#define MTOT (B_ * S_)   // 4096
#define KVDIM (NKV_ * HD_)  // 288

typedef float f32x4 __attribute__((ext_vector_type(4)));
typedef short bf16x8 __attribute__((ext_vector_type(8)));
typedef short s4v __attribute__((ext_vector_type(4)));

__device__ __forceinline__ float bf2f(short x) {
  unsigned int u = ((unsigned int)(unsigned short)x) << 16;
  return __builtin_bit_cast(float, u);
}
__device__ __forceinline__ short f2bf(float f) {
  unsigned int u = __builtin_bit_cast(unsigned int, f);
  u += 0x7fff + ((u >> 16) & 1);   // RNE
  return (short)(u >> 16);
}

__device__ __forceinline__ void async16(const short* g, short* lds) {
  __builtin_amdgcn_global_load_lds((const __attribute__((address_space(1))) void*)g,
                                   (__attribute__((address_space(3))) void*)lds,
                                   16, 0, 0);
}

// ---------------- fp32 -> bf16 convert ----------------
__global__ void k_cvt(const float4* __restrict__ in, s4v* __restrict__ out, int n4) {
  int i = blockIdx.x * blockDim.x + threadIdx.x;
  int stride = gridDim.x * blockDim.x;
  for (; i < n4; i += stride) {
    float4 v = in[i];
    s4v o = { f2bf(v.x), f2bf(v.y), f2bf(v.z), f2bf(v.w) };
    out[i] = o;
  }
}

// ---------------- RoPE table ----------------
__global__ void k_rope_table(float2* __restrict__ tab) {
  int idx = blockIdx.x * blockDim.x + threadIdx.x;
  if (idx >= S_ * 36) return;
  int i = idx % 36, s = idx / 36;
  float freq = powf(10000.0f, -(float)i / 36.0f);
  float a = (float)s * freq;
  tab[idx] = make_float2(cosf(a), sinf(a));
}

// ---------------- RoPE apply (in place on bf16) ----------------
__global__ void k_rope(short* __restrict__ X, const float2* __restrict__ tab,
                       int nh, int stride) {
  int idx = blockIdx.x * blockDim.x + threadIdx.x;
  int total = MTOT * nh * 36;
  if (idx >= total) return;
  int i = idx % 36;
  int t = idx / 36;
  int hh = t % nh;
  int m = t / nh;
  int s = m & (S_ - 1);
  float2 cs = tab[s * 36 + i];
  short* p = X + (size_t)m * stride + hh * HD_;
  float x1 = bf2f(p[i]), x2 = bf2f(p[i + 36]);
  p[i]      = f2bf(x1 * cs.x - x2 * cs.y);
  p[i + 36] = f2bf(x2 * cs.x + x1 * cs.y);
}

// ---------------- V transpose: Vt[bkv][d(80, pad)][s] ----------------
__global__ void k_transpose_v(const short* __restrict__ Vb, short* __restrict__ Vt) {
  int idx = blockIdx.x * blockDim.x + threadIdx.x;
  int total = 8 * 80 * S_;
  if (idx >= total) return;
  int s = idx & (S_ - 1);
  int t2 = idx >> 11;
  int d = t2 % 80;
  int bkv = t2 / 80;
  int b = bkv >> 2, kv = bkv & 3;
  short v = 0;
  if (d < HD_) v = Vb[((size_t)(b * S_ + s)) * KVDIM + kv * HD_ + d];
  Vt[idx] = v;
}

// ---------------- GEMM: C[M,N] = A[M,K] * B[N,K]^T  (bf16 in, fp32 acc) ----------------
#define BM 128
#define BN 128
#define BK 32

template<int OUTF>  // 0 = bf16 out, 1 = f32 out
__global__ __launch_bounds__(256) void k_gemm_bt(const short* __restrict__ A,
                                                 const short* __restrict__ Bm,
                                                 void* __restrict__ C,
                                                 int M, int N, int K) {
  __shared__ short As[BM * BK];
  __shared__ short Bs[BN * BK];
  const int tid = threadIdx.x;
  const int l = tid & 63;
  const int w = tid >> 6;
  const int bm = blockIdx.x * BM;
  const int bn = blockIdx.y * BN;
  const int wr = (w >> 1) * 64;
  const int wc = (w & 1) * 64;
  const int c15 = l & 15, g = l >> 4;
  const int r0 = tid >> 2;
  const int c0 = (tid & 3) * 8;

  f32x4 acc[4][4] = {};

  for (int k0 = 0; k0 < K; k0 += BK) {
#pragma unroll
    for (int it = 0; it < 2; ++it) {
      int ar = bm + it * 64 + r0;
      int br = bn + it * 64 + r0;
      if (br > N - 1) br = N - 1;
      async16(A + (size_t)ar * K + k0 + c0, &As[(it * 64 + r0) * BK + c0]);
      async16(Bm + (size_t)br * K + k0 + c0, &Bs[(it * 64 + r0) * BK + c0]);
    }
    __syncthreads();
    bf16x8 af[4], bfr[4];
#pragma unroll
    for (int t = 0; t < 4; ++t) {
      af[t]  = *(const bf16x8*)&As[(wr + t * 16 + c15) * BK + g * 8];
      bfr[t] = *(const bf16x8*)&Bs[(wc + t * 16 + c15) * BK + g * 8];
    }
#pragma unroll
    for (int mt = 0; mt < 4; ++mt)
#pragma unroll
      for (int nt = 0; nt < 4; ++nt)
        acc[mt][nt] = __builtin_amdgcn_mfma_f32_16x16x32_bf16(af[mt], bfr[nt], acc[mt][nt], 0, 0, 0);
    __syncthreads();
  }

#pragma unroll
  for (int mt = 0; mt < 4; ++mt)
#pragma unroll
    for (int nt = 0; nt < 4; ++nt)
#pragma unroll
      for (int j = 0; j < 4; ++j) {
        int row = bm + wr + mt * 16 + g * 4 + j;
        int col = bn + wc + nt * 16 + c15;
        if (col < N) {
          if (OUTF) ((float*)C)[(size_t)row * N + col] = acc[mt][nt][j];
          else      ((short*)C)[(size_t)row * N + col] = f2bf(acc[mt][nt][j]);
        }
      }
}

// ---------------- Flash attention ----------------
// grid: (64 qtiles of 32 rows, 8 = b*4+kv). 4 waves = 4 q-heads of the kv group.
#define QB 32
#define KT 64

__global__ __launch_bounds__(256) void k_flash(const short* __restrict__ Q,
                                               const short* __restrict__ Kg,
                                               const short* __restrict__ Vt,
                                               short* __restrict__ O) {
  const int qt = blockIdx.x;
  const int bkv = blockIdx.y;
  const int b = bkv >> 2, kv = bkv & 3;
  const int q0 = qt * QB;
  const int tid = threadIdx.x;
  const int w = tid >> 6, l = tid & 63;
  const int c15 = l & 15, g = l >> 4;
  const int h = kv * 4 + w;

  __shared__ short Ks[KT][96];     // [k-col][hd padded 72->96 with zeros]
  __shared__ short Vs[80][72];     // [d padded to 80][k-col, 64 used + 8 pad]
  __shared__ short Ps[4][16][72];  // per-wave P scratch [qrow][kcol, 64 used + pad]

  const float rscale = 0.117851130f;  // 1/sqrt(72)

  // preload Q fragments (hd padded to 96; last 8 lanes-groups zero)
  bf16x8 qf[2][3];
  const bf16x8 zfrag = {0,0,0,0,0,0,0,0};
#pragma unroll
  for (int rt = 0; rt < 2; ++rt) {
    int row = q0 + rt * 16 + c15;
    const short* qrow = Q + ((size_t)(b * S_ + row)) * HID_ + h * HD_;
#pragma unroll
    for (int ks = 0; ks < 3; ++ks) {
      int d0 = ks * 32 + g * 8;
      qf[rt][ks] = (d0 < HD_) ? *(const bf16x8*)(qrow + d0) : zfrag;
    }
  }

  float m_st[2][4], l_st[2][4];
#pragma unroll
  for (int rt = 0; rt < 2; ++rt)
#pragma unroll
    for (int j = 0; j < 4; ++j) { m_st[rt][j] = -1e30f; l_st[rt][j] = 0.f; }
  f32x4 accO[2][5] = {};

  const int nkt = (q0 + QB + KT - 1) / KT;
  for (int kt = 0; kt < nkt; ++kt) {
    const int kbase = kt * KT;
    // stage K tile (zero-pad hd 72..95)
    for (int idx = tid; idx < KT * 48; idx += 256) {
      int kk = idx / 48, cq = idx % 48;
      unsigned int val = 0;
      if (cq < 36) {
        const short* src = Kg + ((size_t)(b * S_ + kbase + kk)) * KVDIM + kv * HD_ + cq * 2;
        val = *(const unsigned int*)src;
      }
      *(unsigned int*)&Ks[kk][cq * 2] = val;
    }
    // stage V^T tile
    for (int idx = tid; idx < 80 * 32; idx += 256) {
      int d = idx >> 5, kk2 = (idx & 31) * 2;
      const short* src = Vt + ((size_t)(bkv * 80 + d)) * S_ + kbase + kk2;
      *(unsigned int*)&Vs[d][kk2] = *(const unsigned int*)src;
    }
    __syncthreads();

#pragma unroll
    for (int rt = 0; rt < 2; ++rt) {
      // QK^T
      f32x4 sc[4] = {};
#pragma unroll
      for (int ct = 0; ct < 4; ++ct)
#pragma unroll
        for (int ks = 0; ks < 3; ++ks) {
          bf16x8 kf = *(const bf16x8*)&Ks[ct * 16 + c15][ks * 32 + g * 8];
          sc[ct] = __builtin_amdgcn_mfma_f32_16x16x32_bf16(qf[rt][ks], kf, sc[ct], 0, 0, 0);
        }
      // mask + scale
      const int qrow = q0 + rt * 16 + g * 4;  // + j
      float pm[4] = {-1e30f, -1e30f, -1e30f, -1e30f};
      float pv[4][4];
#pragma unroll
      for (int ct = 0; ct < 4; ++ct) {
        int col = kbase + ct * 16 + c15;
#pragma unroll
        for (int j = 0; j < 4; ++j) {
          float s = sc[ct][j] * rscale;
          if (col > qrow + j) s = -1e30f;
          pv[ct][j] = s;
          pm[j] = fmaxf(pm[j], s);
        }
      }
      // row max across 16 lanes (stays within l>>4 group)
#pragma unroll
      for (int off = 8; off >= 1; off >>= 1)
#pragma unroll
        for (int j = 0; j < 4; ++j)
          pm[j] = fmaxf(pm[j], __shfl_xor(pm[j], off));
      float rfac[4];
#pragma unroll
      for (int j = 0; j < 4; ++j) {
        float mn = fmaxf(m_st[rt][j], pm[j]);
        rfac[j] = __expf(m_st[rt][j] - mn);
        m_st[rt][j] = mn;
      }
      float rs[4] = {0.f, 0.f, 0.f, 0.f};
#pragma unroll
      for (int ct = 0; ct < 4; ++ct)
#pragma unroll
        for (int j = 0; j < 4; ++j) {
          float p = __expf(pv[ct][j] - m_st[rt][j]);
          pv[ct][j] = p;
          rs[j] += p;
        }
#pragma unroll
      for (int off = 8; off >= 1; off >>= 1)
#pragma unroll
        for (int j = 0; j < 4; ++j)
          rs[j] += __shfl_xor(rs[j], off);
#pragma unroll
      for (int j = 0; j < 4; ++j)
        l_st[rt][j] = l_st[rt][j] * rfac[j] + rs[j];
#pragma unroll
      for (int dt = 0; dt < 5; ++dt)
#pragma unroll
        for (int j = 0; j < 4; ++j)
          accO[rt][dt][j] *= rfac[j];
      // P -> per-wave LDS (D-layout -> A-frag layout)
#pragma unroll
      for (int ct = 0; ct < 4; ++ct)
#pragma unroll
        for (int j = 0; j < 4; ++j)
          Ps[w][g * 4 + j][ct * 16 + c15] = f2bf(pv[ct][j]);
      asm volatile("s_waitcnt lgkmcnt(0)" ::: "memory");
      // PV
#pragma unroll
      for (int ks2 = 0; ks2 < 2; ++ks2) {
        bf16x8 pa = *(const bf16x8*)&Ps[w][c15][ks2 * 32 + g * 8];
#pragma unroll
        for (int dt = 0; dt < 5; ++dt) {
          bf16x8 vb = *(const bf16x8*)&Vs[dt * 16 + c15][ks2 * 32 + g * 8];
          accO[rt][dt] = __builtin_amdgcn_mfma_f32_16x16x32_bf16(pa, vb, accO[rt][dt], 0, 0, 0);
        }
      }
    }
    __syncthreads();
  }

  // epilogue: O[b, s, h*72 + d] = accO / l
#pragma unroll
  for (int rt = 0; rt < 2; ++rt) {
    float inv[4];
#pragma unroll
    for (int j = 0; j < 4; ++j) inv[j] = 1.0f / l_st[rt][j];
#pragma unroll
    for (int dt = 0; dt < 5; ++dt) {
      int d = dt * 16 + c15;
      if (d < HD_) {
#pragma unroll
        for (int j = 0; j < 4; ++j) {
          int row = q0 + rt * 16 + g * 4 + j;
          O[((size_t)(b * S_ + row)) * HID_ + h * HD_ + d] = f2bf(accO[rt][dt][j] * inv[j]);
        }
      }
    }
  }
}

// ---------------- host ----------------
extern "C" void kernel_launch(void* const* d_in, const int* in_sizes, int n_in,
                              void* d_out, int out_size, void* d_ws, size_t ws_size,
                              hipStream_t stream) {
  const float* hs = (const float*)d_in[0];
  // d_in[1] = attention_mask (causal, implemented analytically — unused)
  const float* wq = (const float*)d_in[2];
  const float* wk = (const float*)d_in[3];
  const float* wv = (const float*)d_in[4];
  const float* wo = (const float*)d_in[5];

  char* ws = (char*)d_ws;
  short* Xb  = (short*)(ws + 0);          // 4096x1152 bf16
  short* Qb  = (short*)(ws + 9437184);    // 4096x1152
  short* Kb  = (short*)(ws + 18874368);   // 4096x288
  short* Vb  = (short*)(ws + 21233664);   // 4096x288
  short* Vt  = (short*)(ws + 23592960);   // 8x80x2048
  short* Ob  = (short*)(ws + 26214400);   // 4096x1152
  short* wqb = (short*)(ws + 35651584);   // 1152x1152
  short* wkb = (short*)(ws + 38305792);   // 288x1152
  short* wvb = (short*)(ws + 38969344);   // 288x1152
  short* wob = (short*)(ws + 39632896);   // 1152x1152
  float2* tab = (float2*)(ws + 42287104); // 2048x36 cos/sin

  auto cvt = [&](const float* src, short* dst, int n) {
    int n4 = n / 4;
    int blocks = (n4 + 255) / 256;
    if (blocks > 2048) blocks = 2048;
    k_cvt<<<blocks, 256, 0, stream>>>((const float4*)src, (s4v*)dst, n4);
  };
  cvt(hs, Xb, MTOT * HID_);
  cvt(wq, wqb, HID_ * HID_);
  cvt(wk, wkb, KVDIM * HID_);
  cvt(wv, wvb, KVDIM * HID_);
  cvt(wo, wob, HID_ * HID_);

  k_rope_table<<<(S_ * 36 + 255) / 256, 256, 0, stream>>>(tab);

  k_gemm_bt<0><<<dim3(32, 9), 256, 0, stream>>>(Xb, wqb, Qb, MTOT, HID_, HID_);
  k_gemm_bt<0><<<dim3(32, 3), 256, 0, stream>>>(Xb, wkb, Kb, MTOT, KVDIM, HID_);
  k_gemm_bt<0><<<dim3(32, 3), 256, 0, stream>>>(Xb, wvb, Vb, MTOT, KVDIM, HID_);

  k_rope<<<(MTOT * NH_ * 36 + 255) / 256, 256, 0, stream>>>(Qb, tab, NH_, HID_);
  k_rope<<<(MTOT * NKV_ * 36 + 255) / 256, 256, 0, stream>>>(Kb, tab, NKV_, KVDIM);

  k_transpose_v<<<(8 * 80 * S_ + 255) / 256, 256, 0, stream>>>(Vb, Vt);

  k_flash<<<dim3(64, 8), 256, 0, stream>>>(Qb, Kb, Vt, Ob);

  k_gemm_bt<1><<<dim3(32, 9), 256, 0, stream>>>(Ob, wob, d_out, MTOT, HID_, HID_);
}

// Round 2
// 265.374 us; speedup vs baseline: 1.7135x; 1.7135x over previous
//
#include <hip/hip_runtime.h>
#include <hip/hip_bf16.h>
#include <cstddef>

#define B_   2
#define S_   2048
#define HID_ 1152
#define NH_  16
#define NKV_ 4
#define HD_  72
#define MTOT (B_ * S_)   // 4096
#define KVDIM (NKV_ * HD_)  // 288

typedef float f32x4 __attribute__((ext_vector_type(4)));
typedef short bf16x8 __attribute__((ext_vector_type(8)));
typedef short s4v __attribute__((ext_vector_type(4)));

__device__ __forceinline__ float bf2f(short x) {
  unsigned int u = ((unsigned int)(unsigned short)x) << 16;
  return __builtin_bit_cast(float, u);
}
__device__ __forceinline__ short f2bf(float f) {
  unsigned int u = __builtin_bit_cast(unsigned int, f);
  u += 0x7fff + ((u >> 16) & 1);   // RNE
  return (short)(u >> 16);
}

__device__ __forceinline__ void async16(const short* g, short* lds) {
  __builtin_amdgcn_global_load_lds((const __attribute__((address_space(1))) void*)g,
                                   (__attribute__((address_space(3))) void*)lds,
                                   16, 0, 0);
}

// ---------------- fp32 -> bf16 convert ----------------
__global__ void k_cvt(const float4* __restrict__ in, s4v* __restrict__ out, int n4) {
  int i = blockIdx.x * blockDim.x + threadIdx.x;
  int stride = gridDim.x * blockDim.x;
  for (; i < n4; i += stride) {
    float4 v = in[i];
    s4v o = { f2bf(v.x), f2bf(v.y), f2bf(v.z), f2bf(v.w) };
    out[i] = o;
  }
}

// ---------------- RoPE table ----------------
__global__ void k_rope_table(float2* __restrict__ tab) {
  int idx = blockIdx.x * blockDim.x + threadIdx.x;
  if (idx >= S_ * 36) return;
  int i = idx % 36, s = idx / 36;
  float freq = powf(10000.0f, -(float)i / 36.0f);
  float a = (float)s * freq;
  tab[idx] = make_float2(cosf(a), sinf(a));
}

// ---------------- RoPE apply (in place on bf16) ----------------
__global__ void k_rope(short* __restrict__ X, const float2* __restrict__ tab,
                       int nh, int stride) {
  int idx = blockIdx.x * blockDim.x + threadIdx.x;
  int total = MTOT * nh * 36;
  if (idx >= total) return;
  int i = idx % 36;
  int t = idx / 36;
  int hh = t % nh;
  int m = t / nh;
  int s = m & (S_ - 1);
  float2 cs = tab[s * 36 + i];
  short* p = X + (size_t)m * stride + hh * HD_;
  float x1 = bf2f(p[i]), x2 = bf2f(p[i + 36]);
  p[i]      = f2bf(x1 * cs.x - x2 * cs.y);
  p[i + 36] = f2bf(x2 * cs.x + x1 * cs.y);
}

// ---------------- V transpose: Vt[bkv][d(80, pad)][s] ----------------
__global__ void k_transpose_v(const short* __restrict__ Vb, short* __restrict__ Vt) {
  int idx = blockIdx.x * blockDim.x + threadIdx.x;
  int total = 8 * 80 * S_;
  if (idx >= total) return;
  int s = idx & (S_ - 1);
  int t2 = idx >> 11;
  int d = t2 % 80;
  int bkv = t2 / 80;
  int b = bkv >> 2, kv = bkv & 3;
  short v = 0;
  if (d < HD_) v = Vb[((size_t)(b * S_ + s)) * KVDIM + kv * HD_ + d];
  Vt[idx] = v;
}

// ---------------- GEMM: C[M,N] = A[M,K] * B[N,K]^T  (bf16 in, fp32 acc) ----------------
#define BM 128
#define BN 128
#define BK 32

template<int OUTF>  // 0 = bf16 out, 1 = f32 out
__global__ __launch_bounds__(256) void k_gemm_bt(const short* __restrict__ A,
                                                 const short* __restrict__ Bm,
                                                 void* __restrict__ C,
                                                 int M, int N, int K) {
  __shared__ short As[BM * BK];
  __shared__ short Bs[BN * BK];
  const int tid = threadIdx.x;
  const int l = tid & 63;
  const int w = tid >> 6;
  const int bm = blockIdx.x * BM;
  const int bn = blockIdx.y * BN;
  const int wr = (w >> 1) * 64;
  const int wc = (w & 1) * 64;
  const int c15 = l & 15, g = l >> 4;
  const int r0 = tid >> 2;
  const int c0 = (tid & 3) * 8;

  f32x4 acc[4][4] = {};

  for (int k0 = 0; k0 < K; k0 += BK) {
#pragma unroll
    for (int it = 0; it < 2; ++it) {
      int ar = bm + it * 64 + r0;
      int br = bn + it * 64 + r0;
      if (br > N - 1) br = N - 1;
      async16(A + (size_t)ar * K + k0 + c0, &As[(it * 64 + r0) * BK + c0]);
      async16(Bm + (size_t)br * K + k0 + c0, &Bs[(it * 64 + r0) * BK + c0]);
    }
    __syncthreads();
    bf16x8 af[4], bfr[4];
#pragma unroll
    for (int t = 0; t < 4; ++t) {
      af[t]  = *(const bf16x8*)&As[(wr + t * 16 + c15) * BK + g * 8];
      bfr[t] = *(const bf16x8*)&Bs[(wc + t * 16 + c15) * BK + g * 8];
    }
#pragma unroll
    for (int mt = 0; mt < 4; ++mt)
#pragma unroll
      for (int nt = 0; nt < 4; ++nt)
        acc[mt][nt] = __builtin_amdgcn_mfma_f32_16x16x32_bf16(af[mt], bfr[nt], acc[mt][nt], 0, 0, 0);
    __syncthreads();
  }

#pragma unroll
  for (int mt = 0; mt < 4; ++mt)
#pragma unroll
    for (int nt = 0; nt < 4; ++nt)
#pragma unroll
      for (int j = 0; j < 4; ++j) {
        int row = bm + wr + mt * 16 + g * 4 + j;
        int col = bn + wc + nt * 16 + c15;
        if (col < N) {
          if (OUTF) ((float*)C)[(size_t)row * N + col] = acc[mt][nt][j];
          else      ((short*)C)[(size_t)row * N + col] = f2bf(acc[mt][nt][j]);
        }
      }
}

// ---------------- Flash attention (1 wave per (qt, b, head), no barriers) ----------------
// K/V are L2-resident (288 KB per (b,kv)); read MFMA fragments directly from
// global instead of LDS staging (guide §B / m169). blockIdx decode pins 4
// heads of one kv-group per XCD, qt descending for causal load balance.
#define QB 32
#define KT 64

__global__ __launch_bounds__(64) void k_flash(const short* __restrict__ Q,
                                              const short* __restrict__ Kg,
                                              const short* __restrict__ Vt,
                                              short* __restrict__ O) {
  const int bid = blockIdx.x;
  const int xcd = bid & 7, slot = bid >> 3;
  const int bh = (xcd << 2) | (slot >> 6);   // 4 heads (one kv group) per XCD
  const int qt = 63 - (slot & 63);           // longest blocks first
  const int b = bh >> 4, h = bh & 15, kv = h >> 2;
  const int q0 = qt * QB;
  const int l = threadIdx.x & 63;
  const int c15 = l & 15, g = l >> 4;

  __shared__ short Ps[32][72];   // P transpose scratch (D-layout -> A-frag), wave-local

  const float rscale = 0.117851130f;  // 1/sqrt(72)

  const short* Qbase = Q + (size_t)(b * S_) * HID_ + h * HD_;
  const short* Kbase = Kg + (size_t)(b * S_) * KVDIM + kv * HD_;
  const short* Vbase = Vt + (size_t)(b * NKV_ + kv) * 80 * S_;

  // Q fragments (hd padded 72->96 with zero frags so K-garbage at k>=72 times 0)
  bf16x8 qf[2][3];
  const bf16x8 zfrag = {0, 0, 0, 0, 0, 0, 0, 0};
#pragma unroll
  for (int rt = 0; rt < 2; ++rt) {
    int row = q0 + rt * 16 + c15;
#pragma unroll
    for (int ks = 0; ks < 3; ++ks) {
      int d0 = ks * 32 + g * 8;
      qf[rt][ks] = (d0 < HD_) ? *(const bf16x8*)(Qbase + (size_t)row * HID_ + d0) : zfrag;
    }
  }

  float m_st[2][4], l_st[2][4];
#pragma unroll
  for (int rt = 0; rt < 2; ++rt)
#pragma unroll
    for (int j = 0; j < 4; ++j) { m_st[rt][j] = -1e30f; l_st[rt][j] = 0.f; }
  f32x4 accO[2][5] = {};

  const int nkt = (q0 + QB + KT - 1) / KT;
  const int nfull = (QB * qt + 1) >> 6;   // tiles with no masked element

  for (int kt = 0; kt < nkt; ++kt) {
    const int kbase = kt * KT;
    const short* kp = Kbase + (size_t)kbase * KVDIM;

    // K fragments direct from L2, shared by both row-tiles
    bf16x8 kf[4][3];
#pragma unroll
    for (int ct = 0; ct < 4; ++ct)
#pragma unroll
      for (int ks = 0; ks < 3; ++ks)
        kf[ct][ks] = *(const bf16x8*)(kp + (size_t)(ct * 16 + c15) * KVDIM + ks * 32 + g * 8);

    f32x4 sc[2][4] = {};
#pragma unroll
    for (int rt = 0; rt < 2; ++rt)
#pragma unroll
      for (int ct = 0; ct < 4; ++ct)
#pragma unroll
        for (int ks = 0; ks < 3; ++ks)
          sc[rt][ct] = __builtin_amdgcn_mfma_f32_16x16x32_bf16(qf[rt][ks], kf[ct][ks], sc[rt][ct], 0, 0, 0);

    // V^T fragments issued early so L2 latency hides under softmax VALU
    bf16x8 vf[2][5];
#pragma unroll
    for (int ks2 = 0; ks2 < 2; ++ks2)
#pragma unroll
      for (int dt = 0; dt < 5; ++dt)
        vf[ks2][dt] = *(const bf16x8*)(Vbase + (size_t)(dt * 16 + c15) * S_ + kbase + ks2 * 32 + g * 8);

    const bool masked = (kt >= nfull);

#pragma unroll
    for (int rt = 0; rt < 2; ++rt) {
      const int qrow = q0 + rt * 16 + g * 4;  // + j
      float pm[4] = {-1e30f, -1e30f, -1e30f, -1e30f};
      float pv[4][4];
#pragma unroll
      for (int ct = 0; ct < 4; ++ct) {
        int col = kbase + ct * 16 + c15;
#pragma unroll
        for (int j = 0; j < 4; ++j) {
          float s = sc[rt][ct][j] * rscale;
          if (masked && col > qrow + j) s = -1e30f;
          pv[ct][j] = s;
          pm[j] = fmaxf(pm[j], s);
        }
      }
      // row max across the 16 lanes of this row group
#pragma unroll
      for (int off = 8; off >= 1; off >>= 1)
#pragma unroll
        for (int j = 0; j < 4; ++j)
          pm[j] = fmaxf(pm[j], __shfl_xor(pm[j], off));
      // rescale only when the running max grows (exact-skip)
      bool grow = false;
#pragma unroll
      for (int j = 0; j < 4; ++j) grow = grow || (pm[j] > m_st[rt][j]);
      if (__any(grow)) {
#pragma unroll
        for (int j = 0; j < 4; ++j) {
          float mn = fmaxf(m_st[rt][j], pm[j]);
          float r = __expf(m_st[rt][j] - mn);
          m_st[rt][j] = mn;
          l_st[rt][j] *= r;
#pragma unroll
          for (int dt = 0; dt < 5; ++dt) accO[rt][dt][j] *= r;
        }
      }
      float rs[4] = {0.f, 0.f, 0.f, 0.f};
#pragma unroll
      for (int ct = 0; ct < 4; ++ct)
#pragma unroll
        for (int j = 0; j < 4; ++j) {
          float p = __expf(pv[ct][j] - m_st[rt][j]);
          pv[ct][j] = p;
          rs[j] += p;
        }
#pragma unroll
      for (int off = 8; off >= 1; off >>= 1)
#pragma unroll
        for (int j = 0; j < 4; ++j)
          rs[j] += __shfl_xor(rs[j], off);
#pragma unroll
      for (int j = 0; j < 4; ++j)
        l_st[rt][j] += rs[j];
      // P: D-layout -> A-frag layout via wave-local LDS
#pragma unroll
      for (int ct = 0; ct < 4; ++ct)
#pragma unroll
        for (int j = 0; j < 4; ++j)
          Ps[rt * 16 + g * 4 + j][ct * 16 + c15] = f2bf(pv[ct][j]);
    }
    asm volatile("s_waitcnt lgkmcnt(0)" ::: "memory");
    bf16x8 pa[2][2];
#pragma unroll
    for (int rt = 0; rt < 2; ++rt)
#pragma unroll
      for (int ks2 = 0; ks2 < 2; ++ks2)
        pa[rt][ks2] = *(const bf16x8*)&Ps[rt * 16 + c15][ks2 * 32 + g * 8];
#pragma unroll
    for (int ks2 = 0; ks2 < 2; ++ks2)
#pragma unroll
      for (int dt = 0; dt < 5; ++dt)
#pragma unroll
        for (int rt = 0; rt < 2; ++rt)
          accO[rt][dt] = __builtin_amdgcn_mfma_f32_16x16x32_bf16(pa[rt][ks2], vf[ks2][dt], accO[rt][dt], 0, 0, 0);
  }

  // epilogue: O[b, s, h*72 + d] = accO / l
#pragma unroll
  for (int rt = 0; rt < 2; ++rt) {
    float inv[4];
#pragma unroll
    for (int j = 0; j < 4; ++j) inv[j] = 1.0f / l_st[rt][j];
#pragma unroll
    for (int dt = 0; dt < 5; ++dt) {
      int d = dt * 16 + c15;
      if (d < HD_) {
#pragma unroll
        for (int j = 0; j < 4; ++j) {
          int row = q0 + rt * 16 + g * 4 + j;
          O[(size_t)(b * S_ + row) * HID_ + h * HD_ + d] = f2bf(accO[rt][dt][j] * inv[j]);
        }
      }
    }
  }
}

// ---------------- host ----------------
extern "C" void kernel_launch(void* const* d_in, const int* in_sizes, int n_in,
                              void* d_out, int out_size, void* d_ws, size_t ws_size,
                              hipStream_t stream) {
  const float* hs = (const float*)d_in[0];
  // d_in[1] = attention_mask (causal, implemented analytically — unused)
  const float* wq = (const float*)d_in[2];
  const float* wk = (const float*)d_in[3];
  const float* wv = (const float*)d_in[4];
  const float* wo = (const float*)d_in[5];

  char* ws = (char*)d_ws;
  short* Xb  = (short*)(ws + 0);          // 4096x1152 bf16
  short* Qb  = (short*)(ws + 9437184);    // 4096x1152
  short* Kb  = (short*)(ws + 18874368);   // 4096x288
  short* Vb  = (short*)(ws + 21233664);   // 4096x288
  short* Vt  = (short*)(ws + 23592960);   // 8x80x2048
  short* Ob  = (short*)(ws + 26214400);   // 4096x1152
  short* wqb = (short*)(ws + 35651584);   // 1152x1152
  short* wkb = (short*)(ws + 38305792);   // 288x1152
  short* wvb = (short*)(ws + 38969344);   // 288x1152
  short* wob = (short*)(ws + 39632896);   // 1152x1152
  float2* tab = (float2*)(ws + 42287104); // 2048x36 cos/sin

  auto cvt = [&](const float* src, short* dst, int n) {
    int n4 = n / 4;
    int blocks = (n4 + 255) / 256;
    if (blocks > 2048) blocks = 2048;
    k_cvt<<<blocks, 256, 0, stream>>>((const float4*)src, (s4v*)dst, n4);
  };
  cvt(hs, Xb, MTOT * HID_);
  cvt(wq, wqb, HID_ * HID_);
  cvt(wk, wkb, KVDIM * HID_);
  cvt(wv, wvb, KVDIM * HID_);
  cvt(wo, wob, HID_ * HID_);

  k_rope_table<<<(S_ * 36 + 255) / 256, 256, 0, stream>>>(tab);

  k_gemm_bt<0><<<dim3(32, 9), 256, 0, stream>>>(Xb, wqb, Qb, MTOT, HID_, HID_);
  k_gemm_bt<0><<<dim3(32, 3), 256, 0, stream>>>(Xb, wkb, Kb, MTOT, KVDIM, HID_);
  k_gemm_bt<0><<<dim3(32, 3), 256, 0, stream>>>(Xb, wvb, Vb, MTOT, KVDIM, HID_);

  k_rope<<<(MTOT * NH_ * 36 + 255) / 256, 256, 0, stream>>>(Qb, tab, NH_, HID_);
  k_rope<<<(MTOT * NKV_ * 36 + 255) / 256, 256, 0, stream>>>(Kb, tab, NKV_, KVDIM);

  k_transpose_v<<<(8 * 80 * S_ + 255) / 256, 256, 0, stream>>>(Vb, Vt);

  k_flash<<<2048, 64, 0, stream>>>(Qb, Kb, Vt, Ob);

  k_gemm_bt<1><<<dim3(32, 9), 256, 0, stream>>>(Ob, wob, d_out, MTOT, HID_, HID_);
}